// Round 1
// baseline (80.823 us; speedup 1.0000x reference)
//
#include <hip/hip_runtime.h>
#include <stdint.h>

#define NB 16
#define NC 256
#define NH 48
#define NW 64
#define ND 21
#define HW (NH * NW)
#define ROW_ELEMS (NW * NC)   // one (b,y) row as [pos][c] bf16: 16384 elems = 32KB
#define SOUT_LD (NW + 1)      // padded leading dim for epilogue buffer
#define SOUT_SZ (ND * SOUT_LD)

typedef __bf16 bf16x8 __attribute__((ext_vector_type(8)));
typedef float f32x4 __attribute__((ext_vector_type(4)));

// row layout: [pos][c] bf16, c in 16B chunks of 8; low-3 chunk bits XOR (pos&7).
// 512B per pos. ds_read_b128 / ds_write_b128 on this layout are conflict-free.
__device__ __forceinline__ int sw_addr(int x, int chunk) {
    int cs = (chunk & ~7) | ((chunk ^ x) & 7);
    return x * 256 + (cs << 3);
}
// parity permutation: even x -> pos 0..31, odd x -> pos 32..63.
// d = x'-x is always even, so the 64x64 product splits into two 32x32 blocks.
__device__ __forceinline__ int posx(int x) { return ((x & 1) << 5) | (x >> 1); }

// read 8 consecutive c (coalesced across x-lanes) -> packed bf16x8
__device__ __forceinline__ bf16x8 load_pack8(const float* __restrict__ p, int cbase) {
    bf16x8 v;
#pragma unroll
    for (int j = 0; j < 8; ++j)
        v[j] = (__bf16)p[(size_t)(cbase + j) * HW];
    return v;
}

// ---------- pre-pass: in2 fp32 [b][c][h][w] -> ws bf16 rows (parity+swizzle) --
__global__ void __launch_bounds__(256, 4)
convert_in2(const float* __restrict__ in2, unsigned short* __restrict__ ws) {
    __shared__ unsigned short s[ROW_ELEMS];
    const int tid = threadIdx.x;
    const int b = blockIdx.x / NH, y = blockIdx.x % NH;
    const int x = tid & 63, g0 = tid >> 6;
    const int px = posx(x);
    const float* p = in2 + ((size_t)b * NC * NH + y) * NW + x;
#pragma unroll
    for (int i = 0; i < 8; ++i) {
        const int chunk = g0 * 8 + i;                  // c = chunk*8 .. +7
        bf16x8 v = load_pack8(p, chunk * 8);
        *(bf16x8*)&s[sw_addr(px, chunk)] = v;          // b128, conflict-free
    }
    __syncthreads();
    unsigned short* wr = ws + ((size_t)b * NH + y) * ROW_ELEMS;
#pragma unroll
    for (int i = 0; i < 8; ++i) {
        const int e = (i * 256 + tid) * 8;
        *(bf16x8*)(wr + e) = *(const bf16x8*)(s + e);  // linear, coalesced
    }
}

// ---------- main: block per (b,y); wave = (parity, N-tile); 1 barrier/step ---
__global__ void __launch_bounds__(256, 3)
corr_main(const float* __restrict__ in1, const unsigned short* __restrict__ ws,
          float* __restrict__ out) {
    __shared__ unsigned short s1[ROW_ELEMS];     // 32KB in1 row (resident)
    __shared__ float sout[2 * SOUT_SZ];          // 10.9KB double-buffered epilogue
    const int tid  = threadIdx.x;
    const int b    = blockIdx.x / NH, y = blockIdx.x % NH;
    const int lane = tid & 63, wave = tid >> 6;
    const int m_lo = lane & 15, quad = lane >> 4;
    const int par  = wave & 1, nt = wave >> 1;   // wave -> (parity, N-tile)

    // ---- stage in1 row (register-packed, parity-permuted, conflict-free b128)
    {
        const int x = tid & 63, g0 = tid >> 6;
        const int px = posx(x);
        const float* p = in1 + ((size_t)b * NC * NH + y) * NW + x;
#pragma unroll
        for (int i = 0; i < 8; ++i) {
            const int chunk = g0 * 8 + i;
            bf16x8 v = load_pack8(p, chunk * 8);
            *(bf16x8*)&s1[sw_addr(px, chunk)] = v;
        }
    }
    // zero both epilogue buffers while staging lands
    for (int i = tid; i < 2 * SOUT_SZ; i += 256) sout[i] = 0.0f;

    const int d0 = (y >= 20) ? 0 : (21 - y) >> 1;
    const int d1 = min(20, (67 - y) >> 1);
    const unsigned short* wsb = ws + (size_t)b * NH * ROW_ELEMS;
    const int bpos = par * 32 + 16 * nt + m_lo;  // this lane's B column (pos of x')

    auto load_b = [&](bf16x8 (&bf)[8], int dyi) {
        const unsigned short* row = wsb + (size_t)(y - 20 + 2 * dyi) * ROW_ELEMS;
#pragma unroll
        for (int kb = 0; kb < 8; ++kb)
            bf[kb] = *(const bf16x8*)&row[sw_addr(bpos, 4 * kb + quad)];
    };

    bf16x8 bfA[8], bfB[8];
    load_b(bfA, d0);          // issue early; latency hides under staging+prologue
    __syncthreads();

    // ---- cache A for this wave's parity: A[pos = par*32+16*mm+m_lo][k]
    bf16x8 afrag[2][8];
#pragma unroll
    for (int mm = 0; mm < 2; ++mm) {
        const int pos = par * 32 + 16 * mm + m_lo;
#pragma unroll
        for (int kb = 0; kb < 8; ++kb)
            afrag[mm][kb] = *(const bf16x8*)&s1[sw_addr(pos, 4 * kb + quad)];
    }

    // ---- zero invalid dy planes (coalesced, nontemporal)
    float* outbase = out + (((size_t)b * (ND * ND)) * NH + (size_t)y) * NW;
    for (int dyi = 0; dyi < ND; ++dyi) {
        if (dyi >= d0 && dyi <= d1) continue;
        float* ob = outbase + (size_t)dyi * ND * HW;
        for (int i = tid; i < ND * NW; i += 256)
            __builtin_nontemporal_store(0.0f, &ob[(size_t)(i >> 6) * HW + (i & 63)]);
    }

    const float scale = 1.0f / 256.0f;
    const int xq  = 4 * quad;        // row base within an M-16 tile
    const int xph = 16 * nt + m_lo;  // x' half-index (within parity)

    // one dy step: MFMA with bc, prefetch dy+1 into bn, scatter into sout[cb],
    // drain plane dyi-1 from sout[cb^1]. ONE raw barrier, lgkmcnt only — the
    // B prefetch and the nontemporal stores stay in flight across it.
    auto step = [&](bf16x8 (&bc)[8], bf16x8 (&bn)[8], int dyi, int cb) {
        f32x4 acc0 = {0.f, 0.f, 0.f, 0.f}, acc1 = {0.f, 0.f, 0.f, 0.f};
#pragma unroll
        for (int kb = 0; kb < 8; ++kb) {
            acc0 = __builtin_amdgcn_mfma_f32_16x16x32_bf16(afrag[0][kb], bc[kb], acc0, 0, 0, 0);
            acc1 = __builtin_amdgcn_mfma_f32_16x16x32_bf16(afrag[1][kb], bc[kb], acc1, 0, 0, 0);
        }
        if (dyi < d1) load_b(bn, dyi + 1);   // spans the barrier (no vmcnt drain)

        // scatter band entries: row x = 2*xh+par, plane dxi = xph - xh + 10
        float* sb = sout + cb * SOUT_SZ;
#pragma unroll
        for (int r = 0; r < 4; ++r) {
            {
                const int xh = xq + r;                     // mm = 0
                const int dxi = xph - xh + 10;
                if ((unsigned)dxi <= 20u) sb[dxi * SOUT_LD + 2 * xh + par] = acc0[r];
            }
            {
                const int xh = 16 + xq + r;                // mm = 1
                const int dxi = xph - xh + 10;
                if ((unsigned)dxi <= 20u) sb[dxi * SOUT_LD + 2 * xh + par] = acc1[r];
            }
        }
        // drain previous step's plane from the other buffer (and re-zero it)
        if (dyi > d0) {
            float* sp = sout + (cb ^ 1) * SOUT_SZ;
            float* ob = outbase + (size_t)(dyi - 1) * ND * HW;
            for (int i = tid; i < ND * NW; i += 256) {
                const int pl = i >> 6, x = i & 63;
                float v = sp[pl * SOUT_LD + x];
                __builtin_nontemporal_store(v * scale, &ob[(size_t)pl * HW + x]);
                sp[pl * SOUT_LD + x] = 0.0f;
            }
        }
        __asm__ __volatile__("s_waitcnt lgkmcnt(0)\n\ts_barrier" ::: "memory");
    };

    int dyi = d0, last;
    while (true) {
        step(bfA, bfB, dyi, 0);
        if (++dyi > d1) { last = 0; break; }
        step(bfB, bfA, dyi, 1);
        if (++dyi > d1) { last = 1; break; }
    }
    // final plane drain (visibility guaranteed by last step's barrier)
    {
        float* sp = sout + last * SOUT_SZ;
        float* ob = outbase + (size_t)d1 * ND * HW;
        for (int i = tid; i < ND * NW; i += 256) {
            const int pl = i >> 6, x = i & 63;
            __builtin_nontemporal_store(sp[pl * SOUT_LD + x] * scale, &ob[(size_t)pl * HW + x]);
        }
    }
}

// ---------- fallback (round-1 style) if ws is too small ----------------------
__global__ void __launch_bounds__(256, 2)
corr_fallback(const float* __restrict__ in1, const float* __restrict__ in2,
              float* __restrict__ out) {
    __shared__ unsigned short s1[ROW_ELEMS];
    __shared__ unsigned short s2[ROW_ELEMS];
    const int tid = threadIdx.x;
    const int b = blockIdx.x / NH, y = blockIdx.x % NH;
    const int lane = tid & 63, wave = tid >> 6;
    const int m_lo = lane & 15, quad = lane >> 4;
    const int asub = wave >> 1, bsub = wave & 1;
    {
        const int x = tid & 63, g0 = tid >> 6;
        const float* p = in1 + ((size_t)b * NC * NH + y) * NW + x;
        for (int i = 0; i < 8; ++i) {
            const int chunk = g0 * 8 + i;
            bf16x8 v = load_pack8(p, chunk * 8);
            *(bf16x8*)&s1[sw_addr(x, chunk)] = v;
        }
    }
    __syncthreads();
    bf16x8 afrag[2][8];
    for (int mm = 0; mm < 2; ++mm) {
        const int x = 32 * asub + 16 * mm + m_lo;
        for (int kb = 0; kb < 8; ++kb)
            afrag[mm][kb] = *(const bf16x8*)&s1[sw_addr(x, 4 * kb + quad)];
    }
    const float scale = 1.0f / 256.0f;
    for (int dyi = 0; dyi < ND; ++dyi) {
        const int ys = y + 2 * dyi - 20;
        float* ob = out + (((size_t)b * (ND * ND) + (size_t)dyi * ND) * NH + y) * NW;
        if ((unsigned)ys >= (unsigned)NH) {
            for (int i = tid; i < ND * NW; i += 256)
                ob[(size_t)(i >> 6) * HW + (i & 63)] = 0.0f;
            continue;
        }
        __syncthreads();
        {
            const int x = tid & 63, g0 = tid >> 6;
            const float* p = in2 + ((size_t)b * NC * NH + ys) * NW + x;
            for (int i = 0; i < 8; ++i) {
                const int chunk = g0 * 8 + i;
                bf16x8 v = load_pack8(p, chunk * 8);
                *(bf16x8*)&s2[sw_addr(x, chunk)] = v;
            }
        }
        __syncthreads();
        f32x4 acc[2][2];
        for (int mm = 0; mm < 2; ++mm)
            for (int nn = 0; nn < 2; ++nn) acc[mm][nn] = (f32x4){0.f, 0.f, 0.f, 0.f};
        for (int nn = 0; nn < 2; ++nn) {
            const int xpp = 32 * bsub + 16 * nn + m_lo;
            for (int kb = 0; kb < 8; ++kb) {
                bf16x8 bfrag = *(const bf16x8*)&s2[sw_addr(xpp, 4 * kb + quad)];
                acc[0][nn] = __builtin_amdgcn_mfma_f32_16x16x32_bf16(afrag[0][kb], bfrag, acc[0][nn], 0, 0, 0);
                acc[1][nn] = __builtin_amdgcn_mfma_f32_16x16x32_bf16(afrag[1][kb], bfrag, acc[1][nn], 0, 0, 0);
            }
        }
        for (int mm = 0; mm < 2; ++mm)
            for (int nn = 0; nn < 2; ++nn) {
                const int xb = 32 * asub + 16 * mm + 4 * quad;
                const int xpp = 32 * bsub + 16 * nn + m_lo;
                for (int r = 0; r < 4; ++r) {
                    const int x = xb + r, d = xpp - x;
                    if (d >= -20 && d <= 20 && !(d & 1))
                        ob[(size_t)((d + 20) >> 1) * HW + x] = acc[mm][nn][r] * scale;
                }
            }
        for (int i = tid; i < ND * 20; i += 256) {
            const int dxi = i / 20, j = i - dxi * 20;
            const int dx = 2 * dxi - 20, a = dx < 0 ? -dx : dx;
            if (j < a) {
                const int x = dx < 0 ? j : (NW - dx + j);
                ob[(size_t)dxi * HW + x] = 0.0f;
            }
        }
    }
}

extern "C" void kernel_launch(void* const* d_in, const int* in_sizes, int n_in,
                              void* d_out, int out_size, void* d_ws, size_t ws_size,
                              hipStream_t stream) {
    const float* in1 = (const float*)d_in[0];
    const float* in2 = (const float*)d_in[1];
    float* out = (float*)d_out;
    const size_t need = (size_t)NB * NH * ROW_ELEMS * sizeof(unsigned short);
    if (ws_size >= need) {
        convert_in2<<<dim3(NB * NH), dim3(256), 0, stream>>>(in2, (unsigned short*)d_ws);
        corr_main<<<dim3(NB * NH), dim3(256), 0, stream>>>(in1, (const unsigned short*)d_ws, out);
    } else {
        corr_fallback<<<dim3(NB * NH), dim3(256), 0, stream>>>(in1, in2, out);
    }
}

// Round 2
// 60.105 us; speedup vs baseline: 1.3447x; 1.3447x over previous
//
#include <hip/hip_runtime.h>
#include <stdint.h>

#define NB 16
#define NC 256
#define NH 48
#define NW 64
#define ND 21
#define HW (NH * NW)
#define ROW_ELEMS (NW * NC)   // one (b,y) row as [pos][c] bf16: 16384 elems = 32KB
#define SOUT_LD (NW + 1)      // padded leading dim for epilogue buffer
#define SOUT_SZ (ND * SOUT_LD)
#define NXCD 8
#define NWG (NB * NH)         // 768, divisible by 8

typedef __bf16 bf16x8 __attribute__((ext_vector_type(8)));
typedef float f32x4 __attribute__((ext_vector_type(4)));

// XCD-chunked bijective remap: XCD k (= blockIdx%8) gets contiguous wg range
// [k*96, k*96+96) = batches {2k, 2k+1}, all y. ws slice per XCD = 3MB < 4MB L2.
__device__ __forceinline__ int xcd_wg(int orig) {
    return (orig & (NXCD - 1)) * (NWG / NXCD) + (orig >> 3);
}

// row layout: [pos][c] bf16, c in 16B chunks of 8; low-3 chunk bits XOR (pos&7).
// 512B per pos. ds_read_b128 / ds_write_b128 on this layout are conflict-free.
__device__ __forceinline__ int sw_addr(int x, int chunk) {
    int cs = (chunk & ~7) | ((chunk ^ x) & 7);
    return x * 256 + (cs << 3);
}
// parity permutation: even x -> pos 0..31, odd x -> pos 32..63.
// d = x'-x is always even, so the 64x64 product splits into two 32x32 blocks.
__device__ __forceinline__ int posx(int x) { return ((x & 1) << 5) | (x >> 1); }

// read 8 consecutive c (coalesced across x-lanes) -> packed bf16x8
__device__ __forceinline__ bf16x8 load_pack8(const float* __restrict__ p, int cbase) {
    bf16x8 v;
#pragma unroll
    for (int j = 0; j < 8; ++j)
        v[j] = (__bf16)p[(size_t)(cbase + j) * HW];
    return v;
}

// ---------- pre-pass: in2 fp32 [b][c][h][w] -> ws bf16 rows (parity+swizzle) --
__global__ void __launch_bounds__(256, 4)
convert_in2(const float* __restrict__ in2, unsigned short* __restrict__ ws) {
    __shared__ unsigned short s[ROW_ELEMS];
    const int tid = threadIdx.x;
    const int wg = xcd_wg(blockIdx.x);          // same mapping as corr_main:
    const int b = wg / NH, y = wg % NH;         // ws lines stay dirty in this XCD's L2
    const int x = tid & 63, g0 = tid >> 6;
    const int px = posx(x);
    const float* p = in2 + ((size_t)b * NC * NH + y) * NW + x;
#pragma unroll
    for (int i = 0; i < 8; ++i) {
        const int chunk = g0 * 8 + i;                  // c = chunk*8 .. +7
        bf16x8 v = load_pack8(p, chunk * 8);
        *(bf16x8*)&s[sw_addr(px, chunk)] = v;          // b128, conflict-free
    }
    __syncthreads();
    unsigned short* wr = ws + ((size_t)b * NH + y) * ROW_ELEMS;
#pragma unroll
    for (int i = 0; i < 8; ++i) {
        const int e = (i * 256 + tid) * 8;
        *(bf16x8*)(wr + e) = *(const bf16x8*)(s + e);  // linear, coalesced
    }
}

// ---------- main: block per (b,y); wave = (parity, N-tile); 1 barrier/step ---
__global__ void __launch_bounds__(256, 3)
corr_main(const float* __restrict__ in1, const unsigned short* __restrict__ ws,
          float* __restrict__ out) {
    __shared__ unsigned short s1[ROW_ELEMS];     // 32KB in1 row (resident)
    __shared__ float sout[2 * SOUT_SZ];          // 10.9KB double-buffered epilogue
    const int tid  = threadIdx.x;
    const int wg   = xcd_wg(blockIdx.x);
    const int b    = wg / NH, y = wg % NH;
    const int lane = tid & 63, wave = tid >> 6;
    const int m_lo = lane & 15, quad = lane >> 4;
    const int par  = wave & 1, nt = wave >> 1;   // wave -> (parity, N-tile)

    // ---- stage in1 row (register-packed, parity-permuted, conflict-free b128)
    {
        const int x = tid & 63, g0 = tid >> 6;
        const int px = posx(x);
        const float* p = in1 + ((size_t)b * NC * NH + y) * NW + x;
#pragma unroll
        for (int i = 0; i < 8; ++i) {
            const int chunk = g0 * 8 + i;
            bf16x8 v = load_pack8(p, chunk * 8);
            *(bf16x8*)&s1[sw_addr(px, chunk)] = v;
        }
    }
    // zero both epilogue buffers while staging lands
    for (int i = tid; i < 2 * SOUT_SZ; i += 256) sout[i] = 0.0f;

    const int d0 = (y >= 20) ? 0 : (21 - y) >> 1;
    const int d1 = min(20, (67 - y) >> 1);
    const unsigned short* wsb = ws + (size_t)b * NH * ROW_ELEMS;
    const int bpos = par * 32 + 16 * nt + m_lo;  // this lane's B column (pos of x')

    auto load_b = [&](bf16x8 (&bf)[8], int dyi) {
        const unsigned short* row = wsb + (size_t)(y - 20 + 2 * dyi) * ROW_ELEMS;
#pragma unroll
        for (int kb = 0; kb < 8; ++kb)
            bf[kb] = *(const bf16x8*)&row[sw_addr(bpos, 4 * kb + quad)];
    };

    bf16x8 bfA[8], bfB[8];
    load_b(bfA, d0);          // issue early; latency hides under staging+prologue
    __syncthreads();

    // ---- cache A for this wave's parity: A[pos = par*32+16*mm+m_lo][k]
    bf16x8 afrag[2][8];
#pragma unroll
    for (int mm = 0; mm < 2; ++mm) {
        const int pos = par * 32 + 16 * mm + m_lo;
#pragma unroll
        for (int kb = 0; kb < 8; ++kb)
            afrag[mm][kb] = *(const bf16x8*)&s1[sw_addr(pos, 4 * kb + quad)];
    }

    // ---- zero invalid dy planes (coalesced, nontemporal)
    float* outbase = out + (((size_t)b * (ND * ND)) * NH + (size_t)y) * NW;
    for (int dyi = 0; dyi < ND; ++dyi) {
        if (dyi >= d0 && dyi <= d1) continue;
        float* ob = outbase + (size_t)dyi * ND * HW;
        for (int i = tid; i < ND * NW; i += 256)
            __builtin_nontemporal_store(0.0f, &ob[(size_t)(i >> 6) * HW + (i & 63)]);
    }

    const float scale = 1.0f / 256.0f;
    const int xq  = 4 * quad;        // row base within an M-16 tile
    const int xph = 16 * nt + m_lo;  // x' half-index (within parity)

    // one dy step: FIRST issue prefetch of dy+1 into bn (covers a full step),
    // then MFMA with bc, scatter into sout[cb], drain plane dyi-1 from
    // sout[cb^1]. ONE raw barrier, lgkmcnt only — prefetch and nontemporal
    // stores stay in flight across it.
    auto step = [&](bf16x8 (&bc)[8], bf16x8 (&bn)[8], int dyi, int cb) {
        if (dyi < d1) load_b(bn, dyi + 1);   // issue before MFMA: max cover

        f32x4 acc0 = {0.f, 0.f, 0.f, 0.f}, acc1 = {0.f, 0.f, 0.f, 0.f};
#pragma unroll
        for (int kb = 0; kb < 8; ++kb) {
            acc0 = __builtin_amdgcn_mfma_f32_16x16x32_bf16(afrag[0][kb], bc[kb], acc0, 0, 0, 0);
            acc1 = __builtin_amdgcn_mfma_f32_16x16x32_bf16(afrag[1][kb], bc[kb], acc1, 0, 0, 0);
        }

        // scatter band entries: row x = 2*xh+par, plane dxi = xph - xh + 10
        float* sb = sout + cb * SOUT_SZ;
#pragma unroll
        for (int r = 0; r < 4; ++r) {
            {
                const int xh = xq + r;                     // mm = 0
                const int dxi = xph - xh + 10;
                if ((unsigned)dxi <= 20u) sb[dxi * SOUT_LD + 2 * xh + par] = acc0[r];
            }
            {
                const int xh = 16 + xq + r;                // mm = 1
                const int dxi = xph - xh + 10;
                if ((unsigned)dxi <= 20u) sb[dxi * SOUT_LD + 2 * xh + par] = acc1[r];
            }
        }
        // drain previous step's plane from the other buffer (and re-zero it)
        if (dyi > d0) {
            float* sp = sout + (cb ^ 1) * SOUT_SZ;
            float* ob = outbase + (size_t)(dyi - 1) * ND * HW;
            for (int i = tid; i < ND * NW; i += 256) {
                const int pl = i >> 6, x = i & 63;
                float v = sp[pl * SOUT_LD + x];
                __builtin_nontemporal_store(v * scale, &ob[(size_t)pl * HW + x]);
                sp[pl * SOUT_LD + x] = 0.0f;
            }
        }
        __asm__ __volatile__("s_waitcnt lgkmcnt(0)\n\ts_barrier" ::: "memory");
    };

    int dyi = d0, last;
    while (true) {
        step(bfA, bfB, dyi, 0);
        if (++dyi > d1) { last = 0; break; }
        step(bfB, bfA, dyi, 1);
        if (++dyi > d1) { last = 1; break; }
    }
    // final plane drain (visibility guaranteed by last step's barrier)
    {
        float* sp = sout + last * SOUT_SZ;
        float* ob = outbase + (size_t)d1 * ND * HW;
        for (int i = tid; i < ND * NW; i += 256) {
            const int pl = i >> 6, x = i & 63;
            __builtin_nontemporal_store(sp[pl * SOUT_LD + x] * scale, &ob[(size_t)pl * HW + x]);
        }
    }
}

// ---------- fallback (round-1 style) if ws is too small ----------------------
__global__ void __launch_bounds__(256, 2)
corr_fallback(const float* __restrict__ in1, const float* __restrict__ in2,
              float* __restrict__ out) {
    __shared__ unsigned short s1[ROW_ELEMS];
    __shared__ unsigned short s2[ROW_ELEMS];
    const int tid = threadIdx.x;
    const int b = blockIdx.x / NH, y = blockIdx.x % NH;
    const int lane = tid & 63, wave = tid >> 6;
    const int m_lo = lane & 15, quad = lane >> 4;
    const int asub = wave >> 1, bsub = wave & 1;
    {
        const int x = tid & 63, g0 = tid >> 6;
        const float* p = in1 + ((size_t)b * NC * NH + y) * NW + x;
        for (int i = 0; i < 8; ++i) {
            const int chunk = g0 * 8 + i;
            bf16x8 v = load_pack8(p, chunk * 8);
            *(bf16x8*)&s1[sw_addr(x, chunk)] = v;
        }
    }
    __syncthreads();
    bf16x8 afrag[2][8];
    for (int mm = 0; mm < 2; ++mm) {
        const int x = 32 * asub + 16 * mm + m_lo;
        for (int kb = 0; kb < 8; ++kb)
            afrag[mm][kb] = *(const bf16x8*)&s1[sw_addr(x, 4 * kb + quad)];
    }
    const float scale = 1.0f / 256.0f;
    for (int dyi = 0; dyi < ND; ++dyi) {
        const int ys = y + 2 * dyi - 20;
        float* ob = out + (((size_t)b * (ND * ND) + (size_t)dyi * ND) * NH + y) * NW;
        if ((unsigned)ys >= (unsigned)NH) {
            for (int i = tid; i < ND * NW; i += 256)
                ob[(size_t)(i >> 6) * HW + (i & 63)] = 0.0f;
            continue;
        }
        __syncthreads();
        {
            const int x = tid & 63, g0 = tid >> 6;
            const float* p = in2 + ((size_t)b * NC * NH + ys) * NW + x;
            for (int i = 0; i < 8; ++i) {
                const int chunk = g0 * 8 + i;
                bf16x8 v = load_pack8(p, chunk * 8);
                *(bf16x8*)&s2[sw_addr(x, chunk)] = v;
            }
        }
        __syncthreads();
        f32x4 acc[2][2];
        for (int mm = 0; mm < 2; ++mm)
            for (int nn = 0; nn < 2; ++nn) acc[mm][nn] = (f32x4){0.f, 0.f, 0.f, 0.f};
        for (int nn = 0; nn < 2; ++nn) {
            const int xpp = 32 * bsub + 16 * nn + m_lo;
            for (int kb = 0; kb < 8; ++kb) {
                bf16x8 bfrag = *(const bf16x8*)&s2[sw_addr(xpp, 4 * kb + quad)];
                acc[0][nn] = __builtin_amdgcn_mfma_f32_16x16x32_bf16(afrag[0][kb], bfrag, acc[0][nn], 0, 0, 0);
                acc[1][nn] = __builtin_amdgcn_mfma_f32_16x16x32_bf16(afrag[1][kb], bfrag, acc[1][nn], 0, 0, 0);
            }
        }
        for (int mm = 0; mm < 2; ++mm)
            for (int nn = 0; nn < 2; ++nn) {
                const int xb = 32 * asub + 16 * mm + 4 * quad;
                const int xpp = 32 * bsub + 16 * nn + m_lo;
                for (int r = 0; r < 4; ++r) {
                    const int x = xb + r, d = xpp - x;
                    if (d >= -20 && d <= 20 && !(d & 1))
                        ob[(size_t)((d + 20) >> 1) * HW + x] = acc[mm][nn][r] * scale;
                }
            }
        for (int i = tid; i < ND * 20; i += 256) {
            const int dxi = i / 20, j = i - dxi * 20;
            const int dx = 2 * dxi - 20, a = dx < 0 ? -dx : dx;
            if (j < a) {
                const int x = dx < 0 ? j : (NW - dx + j);
                ob[(size_t)dxi * HW + x] = 0.0f;
            }
        }
    }
}

extern "C" void kernel_launch(void* const* d_in, const int* in_sizes, int n_in,
                              void* d_out, int out_size, void* d_ws, size_t ws_size,
                              hipStream_t stream) {
    const float* in1 = (const float*)d_in[0];
    const float* in2 = (const float*)d_in[1];
    float* out = (float*)d_out;
    const size_t need = (size_t)NB * NH * ROW_ELEMS * sizeof(unsigned short);
    if (ws_size >= need) {
        convert_in2<<<dim3(NWG), dim3(256), 0, stream>>>(in2, (unsigned short*)d_ws);
        corr_main<<<dim3(NWG), dim3(256), 0, stream>>>(in1, (const unsigned short*)d_ws, out);
    } else {
        corr_fallback<<<dim3(NWG), dim3(256), 0, stream>>>(in1, in2, out);
    }
}

// Round 3
// 55.744 us; speedup vs baseline: 1.4499x; 1.0782x over previous
//
#include <hip/hip_runtime.h>
#include <stdint.h>

#define NB 16
#define NC 256
#define NH 48
#define NW 64
#define ND 21
#define HW (NH * NW)
#define ROW_ELEMS (NW * NC)   // one (b,y) row: 16384 bf16 = 32KB
#define SOUT_LD (NW + 1)      // padded leading dim for epilogue buffer
#define SOUT_SZ (ND * SOUT_LD)
#define NXCD 8
#define NWG (NB * NH)         // 768, divisible by 8

typedef __bf16 bf16x8 __attribute__((ext_vector_type(8)));
typedef float f32x4 __attribute__((ext_vector_type(4)));

// XCD-chunked bijective remap: XCD k (= blockIdx%8) gets contiguous wg range
// [k*96, k*96+96) = batches {2k, 2k+1}, all y. ws slice per XCD = 3MB < 4MB L2.
__device__ __forceinline__ int xcd_wg(int orig) {
    return (orig & (NXCD - 1)) * (NWG / NXCD) + (orig >> 3);
}

// ---- s1 (in1) LDS layout: [pos][c] bf16 with XOR swizzle, for afrag ds_reads.
__device__ __forceinline__ int sw_addr(int x, int chunk) {
    int cs = (chunk & ~7) | ((chunk ^ x) & 7);
    return x * 256 + (cs << 3);
}
// parity permutation: even x -> pos 0..31, odd x -> pos 32..63.
// d = x'-x is always even, so the 64x64 product splits into two 32x32 blocks.
__device__ __forceinline__ int posx(int x) { return ((x & 1) << 5) | (x >> 1); }

// ---- ws (in2) GLOBAL layout: fragment order. Per row of 16384 shorts:
//   short_off = w*4096 + kb*512 + unit*8,  unit = l ^ ((w&3)<<1)
// where wave w = (nt<<1)|par owns pos = par*32+16*nt+m_lo, lane l = (quad<<4)|m_lo
// holds chunk = 4*kb+quad (c = chunk*8..+7). A wave's per-kb load is a fully
// coalesced contiguous 1KB (8 full 128B lines); whole slice = contiguous 8KB.
__device__ __forceinline__ int frag_off(int w, int kb, int l) {
    return w * 4096 + kb * 512 + ((l ^ ((w & 3) << 1)) << 3);
}

// read 8 consecutive c (coalesced across x-lanes) -> packed bf16x8
__device__ __forceinline__ bf16x8 load_pack8(const float* __restrict__ p, int cbase) {
    bf16x8 v;
#pragma unroll
    for (int j = 0; j < 8; ++j)
        v[j] = (__bf16)p[(size_t)(cbase + j) * HW];
    return v;
}

// ---------- pre-pass: in2 fp32 [b][c][h][w] -> ws bf16 rows (fragment order) --
__global__ void __launch_bounds__(256, 4)
convert_in2(const float* __restrict__ in2, unsigned short* __restrict__ ws) {
    __shared__ unsigned short s[ROW_ELEMS];
    const int tid = threadIdx.x;
    const int wg = xcd_wg(blockIdx.x);          // same mapping as corr_main:
    const int b = wg / NH, y = wg % NH;         // ws lines stay dirty in this XCD's L2
    const int x = tid & 63, g0 = tid >> 6;
    const int par = x & 1, m_lo = (x >> 1) & 15, nt = x >> 5;
    const int w = (nt << 1) | par;
    const float* p = in2 + ((size_t)b * NC * NH + y) * NW + x;
#pragma unroll
    for (int i = 0; i < 8; ++i) {
        const int chunk = g0 * 8 + i;                  // c = chunk*8 .. +7
        const int kb = chunk >> 2, quad = chunk & 3;
        const int l = (quad << 4) | m_lo;
        bf16x8 v = load_pack8(p, chunk * 8);
        *(bf16x8*)&s[frag_off(w, kb, l)] = v;
    }
    __syncthreads();
    unsigned short* wr = ws + ((size_t)b * NH + y) * ROW_ELEMS;
#pragma unroll
    for (int i = 0; i < 8; ++i) {
        const int e = (i * 256 + tid) * 8;
        *(bf16x8*)(wr + e) = *(const bf16x8*)(s + e);  // linear, coalesced
    }
}

// ---------- main: block per (b,y); wave = (parity, N-tile); 1 barrier/step ---
__global__ void __launch_bounds__(256, 3)
corr_main(const float* __restrict__ in1, const unsigned short* __restrict__ ws,
          float* __restrict__ out) {
    __shared__ unsigned short s1[ROW_ELEMS];     // 32KB in1 row (resident)
    __shared__ float sout[2 * SOUT_SZ];          // 10.9KB double-buffered epilogue
    const int tid  = threadIdx.x;
    const int wg   = xcd_wg(blockIdx.x);
    const int b    = wg / NH, y = wg % NH;
    const int lane = tid & 63, wave = tid >> 6;
    const int m_lo = lane & 15, quad = lane >> 4;
    const int par  = wave & 1, nt = wave >> 1;   // wave -> (parity, N-tile)

    // ---- stage in1 row (register-packed, parity-permuted, conflict-free b128)
    {
        const int x = tid & 63, g0 = tid >> 6;
        const int px = posx(x);
        const float* p = in1 + ((size_t)b * NC * NH + y) * NW + x;
#pragma unroll
        for (int i = 0; i < 8; ++i) {
            const int chunk = g0 * 8 + i;
            bf16x8 v = load_pack8(p, chunk * 8);
            *(bf16x8*)&s1[sw_addr(px, chunk)] = v;
        }
    }
    // zero both epilogue buffers once (pad slots stay zero forever: the scatter
    // band mask is dyi-invariant, every valid slot is overwritten every step)
    for (int i = tid; i < 2 * SOUT_SZ; i += 256) sout[i] = 0.0f;

    const int d0 = (y >= 20) ? 0 : (21 - y) >> 1;
    const int d1 = min(20, (67 - y) >> 1);
    const unsigned short* wsb = ws + (size_t)b * NH * ROW_ELEMS;
    const int slice_off = frag_off(wave, 0, lane);   // + kb*512 walks the slice

    auto load_b = [&](bf16x8 (&bf)[8], int dyi) {
        const unsigned short* row = wsb + (size_t)(y - 20 + 2 * dyi) * ROW_ELEMS + slice_off;
#pragma unroll
        for (int kb = 0; kb < 8; ++kb)
            bf[kb] = *(const bf16x8*)&row[kb * 512];  // contiguous 1KB per instr
    };

    bf16x8 bfA[8], bfB[8];
    load_b(bfA, d0);          // issue early; latency hides under staging+prologue
    __syncthreads();

    // ---- cache A for this wave's parity: A[pos = par*32+16*mm+m_lo][k]
    bf16x8 afrag[2][8];
#pragma unroll
    for (int mm = 0; mm < 2; ++mm) {
        const int pos = par * 32 + 16 * mm + m_lo;
#pragma unroll
        for (int kb = 0; kb < 8; ++kb)
            afrag[mm][kb] = *(const bf16x8*)&s1[sw_addr(pos, 4 * kb + quad)];
    }

    // ---- zero invalid dy planes (coalesced, nontemporal)
    float* outbase = out + (((size_t)b * (ND * ND)) * NH + (size_t)y) * NW;
    for (int dyi = 0; dyi < ND; ++dyi) {
        if (dyi >= d0 && dyi <= d1) continue;
        float* ob = outbase + (size_t)dyi * ND * HW;
        for (int i = tid; i < ND * NW; i += 256)
            __builtin_nontemporal_store(0.0f, &ob[(size_t)(i >> 6) * HW + (i & 63)]);
    }

    const float scale = 1.0f / 256.0f;
    const int xq  = 4 * quad;        // row base within an M-16 tile
    const int xph = 16 * nt + m_lo;  // x' half-index (within parity)
    const int dx0 = tid & 63;        // drain column
    const int dp0 = tid >> 6;        // drain plane base (+4 per k)

    // one dy step:
    //   1. issue B prefetch for dy+1 (contiguous, coalesced; spans the barrier)
    //   2. issue drain ds_reads of plane dyi-1 (latency hides under MFMAs)
    //   3. 16 MFMAs
    //   4. nt-store drained plane (reads already landed)
    //   5. scatter this step's band into sout[cb]
    //   6. lgkmcnt(0) + s_barrier (no vmcnt drain: loads/stores stay in flight)
    auto step = [&](bf16x8 (&bc)[8], bf16x8 (&bn)[8], int dyi, int cb) {
        if (dyi < d1) load_b(bn, dyi + 1);

        const bool have = dyi > d0;
        float dv[6];
        float* sp = sout + (cb ^ 1) * SOUT_SZ;
        if (have) {
#pragma unroll
            for (int k = 0; k < 6; ++k) {
                const int i = dx0 + (dp0 + 4 * k) * 64;
                if (i < ND * NW) dv[k] = sp[(dp0 + 4 * k) * SOUT_LD + dx0];
            }
        }

        f32x4 acc0 = {0.f, 0.f, 0.f, 0.f}, acc1 = {0.f, 0.f, 0.f, 0.f};
#pragma unroll
        for (int kb = 0; kb < 8; ++kb) {
            acc0 = __builtin_amdgcn_mfma_f32_16x16x32_bf16(afrag[0][kb], bc[kb], acc0, 0, 0, 0);
            acc1 = __builtin_amdgcn_mfma_f32_16x16x32_bf16(afrag[1][kb], bc[kb], acc1, 0, 0, 0);
        }

        if (have) {
            float* ob = outbase + (size_t)(dyi - 1) * ND * HW;
#pragma unroll
            for (int k = 0; k < 6; ++k) {
                const int i = dx0 + (dp0 + 4 * k) * 64;
                if (i < ND * NW)
                    __builtin_nontemporal_store(dv[k] * scale,
                                                &ob[(size_t)(dp0 + 4 * k) * HW + dx0]);
            }
        }

        // scatter band entries: row x = 2*xh+par, plane dxi = xph - xh + 10
        float* sb = sout + cb * SOUT_SZ;
#pragma unroll
        for (int r = 0; r < 4; ++r) {
            {
                const int xh = xq + r;                     // mm = 0
                const int dxi = xph - xh + 10;
                if ((unsigned)dxi <= 20u) sb[dxi * SOUT_LD + 2 * xh + par] = acc0[r];
            }
            {
                const int xh = 16 + xq + r;                // mm = 1
                const int dxi = xph - xh + 10;
                if ((unsigned)dxi <= 20u) sb[dxi * SOUT_LD + 2 * xh + par] = acc1[r];
            }
        }
        __asm__ __volatile__("s_waitcnt lgkmcnt(0)\n\ts_barrier" ::: "memory");
    };

    int dyi = d0, last;
    while (true) {
        step(bfA, bfB, dyi, 0);
        if (++dyi > d1) { last = 0; break; }
        step(bfB, bfA, dyi, 1);
        if (++dyi > d1) { last = 1; break; }
    }
    // final plane drain (visibility guaranteed by last step's barrier)
    {
        float* sp = sout + last * SOUT_SZ;
        float* ob = outbase + (size_t)d1 * ND * HW;
        for (int i = tid; i < ND * NW; i += 256) {
            const int pl = i >> 6, x = i & 63;
            __builtin_nontemporal_store(sp[pl * SOUT_LD + x] * scale, &ob[(size_t)pl * HW + x]);
        }
    }
}

// ---------- fallback (round-1 style) if ws is too small ----------------------
__global__ void __launch_bounds__(256, 2)
corr_fallback(const float* __restrict__ in1, const float* __restrict__ in2,
              float* __restrict__ out) {
    __shared__ unsigned short s1[ROW_ELEMS];
    __shared__ unsigned short s2[ROW_ELEMS];
    const int tid = threadIdx.x;
    const int b = blockIdx.x / NH, y = blockIdx.x % NH;
    const int lane = tid & 63, wave = tid >> 6;
    const int m_lo = lane & 15, quad = lane >> 4;
    const int asub = wave >> 1, bsub = wave & 1;
    {
        const int x = tid & 63, g0 = tid >> 6;
        const float* p = in1 + ((size_t)b * NC * NH + y) * NW + x;
        for (int i = 0; i < 8; ++i) {
            const int chunk = g0 * 8 + i;
            bf16x8 v = load_pack8(p, chunk * 8);
            *(bf16x8*)&s1[sw_addr(x, chunk)] = v;
        }
    }
    __syncthreads();
    bf16x8 afrag[2][8];
    for (int mm = 0; mm < 2; ++mm) {
        const int x = 32 * asub + 16 * mm + m_lo;
        for (int kb = 0; kb < 8; ++kb)
            afrag[mm][kb] = *(const bf16x8*)&s1[sw_addr(x, 4 * kb + quad)];
    }
    const float scale = 1.0f / 256.0f;
    for (int dyi = 0; dyi < ND; ++dyi) {
        const int ys = y + 2 * dyi - 20;
        float* ob = out + (((size_t)b * (ND * ND) + (size_t)dyi * ND) * NH + y) * NW;
        if ((unsigned)ys >= (unsigned)NH) {
            for (int i = tid; i < ND * NW; i += 256)
                ob[(size_t)(i >> 6) * HW + (i & 63)] = 0.0f;
            continue;
        }
        __syncthreads();
        {
            const int x = tid & 63, g0 = tid >> 6;
            const float* p = in2 + ((size_t)b * NC * NH + ys) * NW + x;
            for (int i = 0; i < 8; ++i) {
                const int chunk = g0 * 8 + i;
                bf16x8 v = load_pack8(p, chunk * 8);
                *(bf16x8*)&s2[sw_addr(x, chunk)] = v;
            }
        }
        __syncthreads();
        f32x4 acc[2][2];
        for (int mm = 0; mm < 2; ++mm)
            for (int nn = 0; nn < 2; ++nn) acc[mm][nn] = (f32x4){0.f, 0.f, 0.f, 0.f};
        for (int nn = 0; nn < 2; ++nn) {
            const int xpp = 32 * bsub + 16 * nn + m_lo;
            for (int kb = 0; kb < 8; ++kb) {
                bf16x8 bfrag = *(const bf16x8*)&s2[sw_addr(xpp, 4 * kb + quad)];
                acc[0][nn] = __builtin_amdgcn_mfma_f32_16x16x32_bf16(afrag[0][kb], bfrag, acc[0][nn], 0, 0, 0);
                acc[1][nn] = __builtin_amdgcn_mfma_f32_16x16x32_bf16(afrag[1][kb], bfrag, acc[1][nn], 0, 0, 0);
            }
        }
        for (int mm = 0; mm < 2; ++mm)
            for (int nn = 0; nn < 2; ++nn) {
                const int xb = 32 * asub + 16 * mm + 4 * quad;
                const int xpp = 32 * bsub + 16 * nn + m_lo;
                for (int r = 0; r < 4; ++r) {
                    const int x = xb + r, d = xpp - x;
                    if (d >= -20 && d <= 20 && !(d & 1))
                        ob[(size_t)((d + 20) >> 1) * HW + x] = acc[mm][nn][r] * scale;
                }
            }
        for (int i = tid; i < ND * 20; i += 256) {
            const int dxi = i / 20, j = i - dxi * 20;
            const int dx = 2 * dxi - 20, a = dx < 0 ? -dx : dx;
            if (j < a) {
                const int x = dx < 0 ? j : (NW - dx + j);
                ob[(size_t)dxi * HW + x] = 0.0f;
            }
        }
    }
}

extern "C" void kernel_launch(void* const* d_in, const int* in_sizes, int n_in,
                              void* d_out, int out_size, void* d_ws, size_t ws_size,
                              hipStream_t stream) {
    const float* in1 = (const float*)d_in[0];
    const float* in2 = (const float*)d_in[1];
    float* out = (float*)d_out;
    const size_t need = (size_t)NB * NH * ROW_ELEMS * sizeof(unsigned short);
    if (ws_size >= need) {
        convert_in2<<<dim3(NWG), dim3(256), 0, stream>>>(in2, (unsigned short*)d_ws);
        corr_main<<<dim3(NWG), dim3(256), 0, stream>>>(in1, (const unsigned short*)d_ws, out);
    } else {
        corr_fallback<<<dim3(NWG), dim3(256), 0, stream>>>(in1, in2, out);
    }
}